// Round 8
// baseline (926.681 us; speedup 1.0000x reference)
//
#include <hip/hip_runtime.h>

// Problem constants
#define BB   4
#define CIN  64
#define HH   256
#define WW   256
#define QQ   256
#define KK   16

typedef _Float16 half8 __attribute__((ext_vector_type(8)));
typedef float   f32x16 __attribute__((ext_vector_type(16)));
typedef unsigned int u32;

// ---- workspace layout (bytes) ----
// w1r/w2r: swizzled DMA weight images; wmu2/lgb: folded head
// act0: fp16 [4][HW][64] = 32 MB (always)
// act1: fp16 [HW][256] = 32 MB (per-batch) or [4][HW][256] = 128 MB (fused)
#define OFF_W1R   0ull
#define OFF_W2R   294912ull
#define OFF_WMU   1474560ull
#define OFF_LGB   1490944ull
#define OFF_ACT0  1605888ull
#define OFF_ACT1  35160320ull
#define WS_FUSED  169378048ull   // 1.6 + 32 + 128 MB

__device__ __forceinline__ void dma16(const void* g, void* l) {
  __builtin_amdgcn_global_load_lds(
      (const __attribute__((address_space(1))) u32*)g,
      (__attribute__((address_space(3))) u32*)l, 16, 0, 0);
}

// ---------------------------------------------------------------------------
// Prep. Blocks 0..575: w1r; 576..2879: w2r; 2880..2895: wmu2+lgb (1 blk/k).
// Weight image block (cc,tt)=16KB: 256 rows x 32ch; 16B-quarter q of row n
// stored at slot q^((n>>1)&3) (bank-group-uniform b128 reads).
// ---------------------------------------------------------------------------
__global__ __launch_bounds__(256) void k_prep(
    const float* __restrict__ w1, const float* __restrict__ w2,
    const float* __restrict__ w3, const float* __restrict__ b3,
    const float* __restrict__ mu,
    _Float16* __restrict__ w1r, _Float16* __restrict__ w2r,
    float* __restrict__ wmu2, float* __restrict__ lgb) {
  int bid = blockIdx.x, tid = threadIdx.x;
  if (bid < 576) {                          // w1r (CI=64): 18 blocks x 8 KB
    int idx = bid * 256 + tid;
    int blk = idx >> 13;
    int cc = blk / 9, tt = blk - cc * 9;
    int rem = idx & 8191;
    int n = rem >> 5, r = rem & 31;
    int q = (r >> 3) ^ ((n >> 1) & 3), e = r & 7;
    int c = cc * 32 + q * 8 + e;
    w1r[idx] = (_Float16)w1[(n * 64 + c) * 9 + tt];
  } else if (bid < 2880) {                  // w2r (CI=256): 72 blocks x 16 KB
    int d = (bid - 576) * 256 + tid;
    int blk = d >> 13;
    int cc = blk / 9, tt = blk - cc * 9;
    int rem = d & 8191;
    int n = rem >> 5, r = rem & 31;
    int q = (r >> 3) ^ ((n >> 1) & 3), e = r & 7;
    int c = cc * 32 + q * 8 + e;
    w2r[d] = (_Float16)w2[(n * 256 + c) * 9 + tt];
  } else {                                  // head fold, one block per k
    int k = bid - 2880;
    float s = 0.f;
    for (int o = 0; o < 256; ++o)
      s = fmaf(mu[k * 256 + o], w3[o * 256 + tid], s);   // w3 coalesced
    wmu2[k * 256 + tid] = 2.f * s;
    float m = mu[k * 256 + tid];
    __shared__ float red[256];
    red[tid] = m * (2.f * b3[tid] - m);
    __syncthreads();
    for (int st = 128; st > 0; st >>= 1) {
      if (tid < st) red[tid] += red[tid + st];
      __syncthreads();
    }
    if (tid == 0) lgb[k] = red[0];
  }
}

// ---------------------------------------------------------------------------
// T0: x NCHW fp32 -> act0 [b][HW][64] fp16, all 4 batches. grid 4096.
// ---------------------------------------------------------------------------
__global__ __launch_bounds__(256) void k_t0(const float* __restrict__ x,
                                            _Float16* __restrict__ act0) {
  __shared__ float tile[64][65];
  int blk = blockIdx.x;
  int b = blk >> 10;
  int p0 = (blk & 1023) << 6;
  int t = threadIdx.x;
  {
    int p = t & 63, c0 = t >> 6;
    const float* xb = x + (size_t)b * (CIN * 65536) + p0 + p;
#pragma unroll
    for (int i = 0; i < 16; ++i) {
      int c = c0 + (i << 2);
      tile[c][p] = xb[(size_t)c * 65536];
    }
  }
  __syncthreads();
  {
    int c = t & 63, p1 = t >> 6;
    _Float16* o = act0 + ((size_t)b * 65536 + p0) * CIN + c;
#pragma unroll
    for (int i = 0; i < 16; ++i) {
      int p = p1 + (i << 2);
      o[(size_t)p * CIN] = (_Float16)tile[c][p];
    }
  }
}

// ---------------------------------------------------------------------------
// Conv1 3x3 (replicate pad) + bias + ReLU, 32x32x16 fp16 MFMA, DMA staging,
// XOR-swizzled LDS. Block: 128 px x 256 ch. grid 512*NB; b = blockIdx>>9.
// ---------------------------------------------------------------------------
template <int CI>
__global__ __launch_bounds__(256, 2) void k_conv(
    const _Float16* __restrict__ actin, const char* __restrict__ wr,
    const float* __restrict__ bias, _Float16* __restrict__ actout) {
  constexpr int NC = CI / 32;
  constexpr int NT = 9 * NC;
  __shared__ __align__(16) char As[2][12288];
  __shared__ __align__(16) char Bs[2][16384];

  int tid = threadIdx.x;
  int b = blockIdx.x >> 9;
  int tile = blockIdx.x & 511;
  int txi = tile & 15, tyi = tile >> 4;
  int x0 = txi << 4, y0 = tyi << 3;
  int lane = tid & 63, wave = tid >> 6;
  int mwave = wave >> 1, nwave = wave & 1;
  int l31 = lane & 31, khalf = lane >> 5;

  f32x16 acc[2][4];
#pragma unroll
  for (int s = 0; s < 2; ++s)
#pragma unroll
    for (int nt = 0; nt < 4; ++nt)
#pragma unroll
      for (int r = 0; r < 16; ++r) acc[s][nt][r] = 0.f;

  const char* aG[3];
  int aL[3];
#pragma unroll
  for (int i = 0; i < 3; ++i) {
    int px = (wave * 3 + i) * 16 + (lane >> 2);
    int s = lane & 3;
    int pxc = min(px, 179);
    int hy = pxc / 18, hx = pxc - hy * 18;
    int y = min(max(y0 - 1 + hy, 0), 255);
    int x = min(max(x0 - 1 + hx, 0), 255);
    int q = s ^ ((pxc >> 1) & 3);
    aG[i] = (const char*)actin +
            (((size_t)(b * 65536 + y * 256 + x)) * CI + q * 8) * 2;
    aL[i] = (wave * 3 + i) * 1024;
  }
  const char* bG = wr + wave * 4096 + lane * 16;
  int bL = wave * 4096;

#pragma unroll
  for (int i = 0; i < 3; ++i) dma16(aG[i], &As[0][aL[i]]);
#pragma unroll
  for (int i = 0; i < 4; ++i) dma16(bG + i * 1024, &Bs[0][bL + i * 1024]);
  __syncthreads();

  for (int cc = 0; cc < NC; ++cc) {
#pragma unroll
    for (int t = 0; t < 9; ++t) {
      int j = cc * 9 + t;
      if (j + 1 < NT) {
        const char* bsrc = bG + (size_t)(j + 1) * 16384;
        char* bdst = &Bs[(j + 1) & 1][bL];
#pragma unroll
        for (int i = 0; i < 4; ++i) dma16(bsrc + i * 1024, bdst + i * 1024);
        if (t == 8) {
#pragma unroll
          for (int i = 0; i < 3; ++i)
            dma16(aG[i] + (cc + 1) * 64, &As[(cc + 1) & 1][aL[i]]);
        }
      }
      int dy = t / 3, dx = t - dy * 3;
      const char* Ab = As[cc & 1];
      const char* Bb = Bs[j & 1];
      half8 af[2][2], bf[2][4];
#pragma unroll
      for (int s = 0; s < 2; ++s) {
        int px = (mwave * 4 + s * 2 + (l31 >> 4) + dy) * 18 + (l31 & 15) + dx;
        int sw = ((px >> 1) & 3) << 4;
#pragma unroll
        for (int ks = 0; ks < 2; ++ks) {
          int q = (ks * 2 + khalf) << 4;
          af[ks][s] = *(const half8*)(Ab + px * 64 + (q ^ sw));
        }
      }
#pragma unroll
      for (int nt = 0; nt < 4; ++nt) {
        int n = nwave * 128 + nt * 32 + l31;
        int sw = ((n >> 1) & 3) << 4;
#pragma unroll
        for (int ks = 0; ks < 2; ++ks) {
          int q = (ks * 2 + khalf) << 4;
          bf[ks][nt] = *(const half8*)(Bb + n * 64 + (q ^ sw));
        }
      }
#pragma unroll
      for (int ks = 0; ks < 2; ++ks)
#pragma unroll
        for (int s = 0; s < 2; ++s)
#pragma unroll
          for (int nt = 0; nt < 4; ++nt)
            acc[s][nt] = __builtin_amdgcn_mfma_f32_32x32x16_f16(
                af[ks][s], bf[ks][nt], acc[s][nt], 0, 0, 0);
      __syncthreads();
    }
  }

#pragma unroll
  for (int s = 0; s < 2; ++s)
#pragma unroll
    for (int nt = 0; nt < 4; ++nt) {
      int n = nwave * 128 + nt * 32 + l31;
      float bn = bias[n];
#pragma unroll
      for (int r = 0; r < 16; ++r) {
        int mrow = (r & 3) + 8 * (r >> 2) + 4 * khalf;
        int y = y0 + mwave * 4 + s * 2 + (mrow >> 4);
        int x = x0 + (mrow & 15);
        float v = fmaxf(acc[s][nt][r] + bn, 0.f);
        actout[(((size_t)(b * 65536 + y * 256 + x)) << 8) + n] = (_Float16)v;
      }
    }
}

// ---------------------------------------------------------------------------
// Conv2 (CI=256) + bias + ReLU + clustering head, fused. K-loop identical to
// k_conv; epilogue stages a2 (fp32) into dead LDS in four 32-px chunks and
// runs the head (logit = wmu2.a2 + lgb, softmax over 16, label dot) there.
// No act2 buffer, writes out[] float directly. grid 512*NB.
// ---------------------------------------------------------------------------
__global__ __launch_bounds__(256, 2) void k_conv2h(
    const _Float16* __restrict__ actin, const char* __restrict__ wr,
    const float* __restrict__ bias, const float* __restrict__ wmu2,
    const float* __restrict__ lgb, const float* __restrict__ label,
    float* __restrict__ out) {
  constexpr int NC = 8;
  constexpr int NT = 72;
  __shared__ __align__(16) char smem[57344];
  auto As = (char(*)[12288])smem;            // [2][12288]
  auto Bs = (char(*)[16384])(smem + 24576);  // [2][16384]
  float* Qs = (float*)smem;                  // epilogue: [32][264] fp32

  int tid = threadIdx.x;
  int b = blockIdx.x >> 9;
  int tile = blockIdx.x & 511;
  int txi = tile & 15, tyi = tile >> 4;
  int x0 = txi << 4, y0 = tyi << 3;
  int lane = tid & 63, wave = tid >> 6;
  int mwave = wave >> 1, nwave = wave & 1;
  int l31 = lane & 31, khalf = lane >> 5;

  f32x16 acc[2][4];
#pragma unroll
  for (int s = 0; s < 2; ++s)
#pragma unroll
    for (int nt = 0; nt < 4; ++nt)
#pragma unroll
      for (int r = 0; r < 16; ++r) acc[s][nt][r] = 0.f;

  const char* aG[3];
  int aL[3];
#pragma unroll
  for (int i = 0; i < 3; ++i) {
    int px = (wave * 3 + i) * 16 + (lane >> 2);
    int s = lane & 3;
    int pxc = min(px, 179);
    int hy = pxc / 18, hx = pxc - hy * 18;
    int y = min(max(y0 - 1 + hy, 0), 255);
    int x = min(max(x0 - 1 + hx, 0), 255);
    int q = s ^ ((pxc >> 1) & 3);
    aG[i] = (const char*)actin +
            (((size_t)(b * 65536 + y * 256 + x)) * 256 + q * 8) * 2;
    aL[i] = (wave * 3 + i) * 1024;
  }
  const char* bG = wr + wave * 4096 + lane * 16;
  int bL = wave * 4096;

#pragma unroll
  for (int i = 0; i < 3; ++i) dma16(aG[i], &As[0][aL[i]]);
#pragma unroll
  for (int i = 0; i < 4; ++i) dma16(bG + i * 1024, &Bs[0][bL + i * 1024]);
  __syncthreads();

  for (int cc = 0; cc < NC; ++cc) {
#pragma unroll
    for (int t = 0; t < 9; ++t) {
      int j = cc * 9 + t;
      if (j + 1 < NT) {
        const char* bsrc = bG + (size_t)(j + 1) * 16384;
        char* bdst = &Bs[(j + 1) & 1][bL];
#pragma unroll
        for (int i = 0; i < 4; ++i) dma16(bsrc + i * 1024, bdst + i * 1024);
        if (t == 8) {
#pragma unroll
          for (int i = 0; i < 3; ++i)
            dma16(aG[i] + (cc + 1) * 64, &As[(cc + 1) & 1][aL[i]]);
        }
      }
      int dy = t / 3, dx = t - dy * 3;
      const char* Ab = As[cc & 1];
      const char* Bb = Bs[j & 1];
      half8 af[2][2], bf[2][4];
#pragma unroll
      for (int s = 0; s < 2; ++s) {
        int px = (mwave * 4 + s * 2 + (l31 >> 4) + dy) * 18 + (l31 & 15) + dx;
        int sw = ((px >> 1) & 3) << 4;
#pragma unroll
        for (int ks = 0; ks < 2; ++ks) {
          int q = (ks * 2 + khalf) << 4;
          af[ks][s] = *(const half8*)(Ab + px * 64 + (q ^ sw));
        }
      }
#pragma unroll
      for (int nt = 0; nt < 4; ++nt) {
        int n = nwave * 128 + nt * 32 + l31;
        int sw = ((n >> 1) & 3) << 4;
#pragma unroll
        for (int ks = 0; ks < 2; ++ks) {
          int q = (ks * 2 + khalf) << 4;
          bf[ks][nt] = *(const half8*)(Bb + n * 64 + (q ^ sw));
        }
      }
#pragma unroll
      for (int ks = 0; ks < 2; ++ks)
#pragma unroll
        for (int s = 0; s < 2; ++s)
#pragma unroll
          for (int nt = 0; nt < 4; ++nt)
            acc[s][nt] = __builtin_amdgcn_mfma_f32_32x32x16_f16(
                af[ks][s], bf[ks][nt], acc[s][nt], 0, 0, 0);
      __syncthreads();
    }
  }

  // ---- fused head epilogue: 4 chunks of 32 px (2 y-rows each) ----
  int pixl = tid >> 3, part = tid & 7;
#pragma unroll
  for (int ch = 0; ch < 4; ++ch) {
    int s = ch >> 1, h = ch & 1;
    // stage a2 = relu(acc + bias) as fp32 into Qs[32][264]
#pragma unroll
    for (int nt = 0; nt < 4; ++nt) {
      int n = nwave * 128 + nt * 32 + l31;
      float bn = bias[n];
#pragma unroll
      for (int rr = 0; rr < 8; ++rr) {
        int r = h * 8 + rr;
        int mrow = (r & 3) + 8 * (r >> 2) + 4 * khalf;
        int pl = mwave * 16 + (mrow & 15);
        Qs[pl * 264 + n] = fmaxf(acc[s][nt][r] + bn, 0.f);
      }
    }
    __syncthreads();
    // head: 8 lanes/px, 32 ch each, staggered starts (conflict-free)
    float cross[16];
#pragma unroll
    for (int k = 0; k < 16; ++k) cross[k] = 0.f;
#pragma unroll
    for (int i = 0; i < 8; ++i) {
      int c4 = (part << 5) + (((i + part) << 2) & 31);
      const float* qp = &Qs[pixl * 264 + c4];
      float q0 = qp[0], q1 = qp[1], q2 = qp[2], q3 = qp[3];
#pragma unroll
      for (int k = 0; k < 16; ++k) {
        const float4 m4 = *(const float4*)(wmu2 + (k << 8) + c4);
        cross[k] = fmaf(q0, m4.x,
                   fmaf(q1, m4.y, fmaf(q2, m4.z, fmaf(q3, m4.w, cross[k]))));
      }
    }
#pragma unroll
    for (int k = 0; k < 16; ++k) {
      cross[k] += __shfl_xor(cross[k], 1, 64);
      cross[k] += __shfl_xor(cross[k], 2, 64);
      cross[k] += __shfl_xor(cross[k], 4, 64);
    }
    float mx = -1e30f, lg[16];
#pragma unroll
    for (int k = 0; k < 16; ++k) {
      lg[k] = cross[k] + lgb[k];
      mx = fmaxf(mx, lg[k]);
    }
    float num = 0.f, den = 0.f;
#pragma unroll
    for (int k = 0; k < 16; ++k) {
      float e = __expf(lg[k] - mx);
      num = fmaf(e, label[k], num);
      den += e;
    }
    if (part == 0) {
      int y = y0 + (pixl >> 4) * 4 + s * 2 + h;
      int x = x0 + (pixl & 15);
      out[(size_t)b * 65536 + y * 256 + x] = num / den;
    }
    __syncthreads();   // Qs reads done before next chunk overwrites
  }
}

// ---------------------------------------------------------------------------
extern "C" void kernel_launch(void* const* d_in, const int* in_sizes, int n_in,
                              void* d_out, int out_size, void* d_ws, size_t ws_size,
                              hipStream_t stream) {
  const float* x  = (const float*)d_in[0];
  const float* w1 = (const float*)d_in[1];
  const float* b1 = (const float*)d_in[2];
  const float* w2 = (const float*)d_in[3];
  const float* b2 = (const float*)d_in[4];
  const float* w3 = (const float*)d_in[5];
  const float* b3 = (const float*)d_in[6];
  const float* mu = (const float*)d_in[7];
  const float* label = (const float*)d_in[8];
  float* out = (float*)d_out;

  char* ws = (char*)d_ws;
  _Float16* w1r  = (_Float16*)(ws + OFF_W1R);
  _Float16* w2r  = (_Float16*)(ws + OFF_W2R);
  float*    wmu2 = (float*)   (ws + OFF_WMU);
  float*    lgb  = (float*)   (ws + OFF_LGB);
  _Float16* act0 = (_Float16*)(ws + OFF_ACT0);   // [4][HW][64]
  _Float16* act1 = (_Float16*)(ws + OFF_ACT1);   // 32 MB (or 128 MB fused)

  k_prep<<<2896, 256, 0, stream>>>(w1, w2, w3, b3, mu, w1r, w2r, wmu2, lgb);
  k_t0<<<4096, 256, 0, stream>>>(x, act0);

  if (ws_size >= WS_FUSED) {
    k_conv<64><<<2048, 256, 0, stream>>>(act0, (const char*)w1r, b1, act1);
    k_conv2h<<<2048, 256, 0, stream>>>(act1, (const char*)w2r, b2,
                                       wmu2, lgb, label, out);
  } else {
    for (int b = 0; b < BB; ++b) {
      k_conv<64><<<512, 256, 0, stream>>>(act0 + (size_t)b * 65536 * CIN,
                                          (const char*)w1r, b1, act1);
      k_conv2h<<<512, 256, 0, stream>>>(act1, (const char*)w2r, b2,
                                        wmu2, lgb, label, out + (size_t)b * 65536);
    }
  }
}

// Round 9
// 774.450 us; speedup vs baseline: 1.1966x; 1.1966x over previous
//
#include <hip/hip_runtime.h>

// Problem constants
#define BB   4
#define CIN  64
#define HH   256
#define WW   256
#define QQ   256
#define KK   16

typedef _Float16 half8 __attribute__((ext_vector_type(8)));
typedef float   f32x16 __attribute__((ext_vector_type(16)));
typedef unsigned int u32;

// ---- workspace layout (bytes); r8 proved ws_size >= 169378048 ----
// w1r/w2r: swizzled DMA weight images; wmu2/lgb: folded head
// act0: fp16 [4][HW][64] = 32 MB (t0 out; dead after conv1 -> reused as act2)
// act1: fp16 [4][HW][256] = 128 MB (conv1 out)
// act2: fp16 [HW][256] = 32 MB, aliased over act0 (per-batch conv2 out)
#define OFF_W1R   0ull
#define OFF_W2R   294912ull
#define OFF_WMU   1474560ull
#define OFF_LGB   1490944ull
#define OFF_ACT0  1605888ull
#define OFF_ACT1  35160320ull
// end of act1 = 169378048 = guaranteed ws floor

__device__ __forceinline__ void dma16(const void* g, void* l) {
  __builtin_amdgcn_global_load_lds(
      (const __attribute__((address_space(1))) u32*)g,
      (__attribute__((address_space(3))) u32*)l, 16, 0, 0);
}

// ---------------------------------------------------------------------------
// Prep. Blocks 0..575: w1r; 576..2879: w2r; 2880..2895: wmu2+lgb (1 blk/k).
// Weight image block (cc,tt)=16KB: 256 rows x 32ch; 16B-quarter q of row n
// stored at slot q^((n>>1)&3) (bank-group-uniform b128 reads).
// ---------------------------------------------------------------------------
__global__ __launch_bounds__(256) void k_prep(
    const float* __restrict__ w1, const float* __restrict__ w2,
    const float* __restrict__ w3, const float* __restrict__ b3,
    const float* __restrict__ mu,
    _Float16* __restrict__ w1r, _Float16* __restrict__ w2r,
    float* __restrict__ wmu2, float* __restrict__ lgb) {
  int bid = blockIdx.x, tid = threadIdx.x;
  if (bid < 576) {                          // w1r (CI=64)
    int idx = bid * 256 + tid;
    int blk = idx >> 13;
    int cc = blk / 9, tt = blk - cc * 9;
    int rem = idx & 8191;
    int n = rem >> 5, r = rem & 31;
    int q = (r >> 3) ^ ((n >> 1) & 3), e = r & 7;
    int c = cc * 32 + q * 8 + e;
    w1r[idx] = (_Float16)w1[(n * 64 + c) * 9 + tt];
  } else if (bid < 2880) {                  // w2r (CI=256)
    int d = (bid - 576) * 256 + tid;
    int blk = d >> 13;
    int cc = blk / 9, tt = blk - cc * 9;
    int rem = d & 8191;
    int n = rem >> 5, r = rem & 31;
    int q = (r >> 3) ^ ((n >> 1) & 3), e = r & 7;
    int c = cc * 32 + q * 8 + e;
    w2r[d] = (_Float16)w2[(n * 256 + c) * 9 + tt];
  } else {                                  // head fold, one block per k
    int k = bid - 2880;
    float s = 0.f;
    for (int o = 0; o < 256; ++o)
      s = fmaf(mu[k * 256 + o], w3[o * 256 + tid], s);   // w3 coalesced
    wmu2[k * 256 + tid] = 2.f * s;
    float m = mu[k * 256 + tid];
    __shared__ float red[256];
    red[tid] = m * (2.f * b3[tid] - m);
    __syncthreads();
    for (int st = 128; st > 0; st >>= 1) {
      if (tid < st) red[tid] += red[tid + st];
      __syncthreads();
    }
    if (tid == 0) lgb[k] = red[0];
  }
}

// ---------------------------------------------------------------------------
// T0: x NCHW fp32 -> act0 [b][HW][64] fp16, all 4 batches. grid 4096.
// ---------------------------------------------------------------------------
__global__ __launch_bounds__(256) void k_t0(const float* __restrict__ x,
                                            _Float16* __restrict__ act0) {
  __shared__ float tile[64][65];
  int blk = blockIdx.x;
  int b = blk >> 10;
  int p0 = (blk & 1023) << 6;
  int t = threadIdx.x;
  {
    int p = t & 63, c0 = t >> 6;
    const float* xb = x + (size_t)b * (CIN * 65536) + p0 + p;
#pragma unroll
    for (int i = 0; i < 16; ++i) {
      int c = c0 + (i << 2);
      tile[c][p] = xb[(size_t)c * 65536];
    }
  }
  __syncthreads();
  {
    int c = t & 63, p1 = t >> 6;
    _Float16* o = act0 + ((size_t)b * 65536 + p0) * CIN + c;
#pragma unroll
    for (int i = 0; i < 16; ++i) {
      int p = p1 + (i << 2);
      o[(size_t)p * CIN] = (_Float16)tile[c][p];
    }
  }
}

// ---------------------------------------------------------------------------
// Conv 3x3 (replicate pad) + bias + ReLU, 32x32x16 fp16 MFMA, DMA staging,
// XOR-swizzled LDS (slot = q ^ ((row>>1)&3)). Block: 128 px x 256 ch.
// grid 512*NB; b = blockIdx>>9 (pass batch-sliced pointers for per-batch).
// ---------------------------------------------------------------------------
template <int CI>
__global__ __launch_bounds__(256, 2) void k_conv(
    const _Float16* __restrict__ actin, const char* __restrict__ wr,
    const float* __restrict__ bias, _Float16* __restrict__ actout) {
  constexpr int NC = CI / 32;
  constexpr int NT = 9 * NC;
  __shared__ __align__(16) char As[2][12288];
  __shared__ __align__(16) char Bs[2][16384];

  int tid = threadIdx.x;
  int b = blockIdx.x >> 9;
  int tile = blockIdx.x & 511;
  int txi = tile & 15, tyi = tile >> 4;
  int x0 = txi << 4, y0 = tyi << 3;
  int lane = tid & 63, wave = tid >> 6;
  int mwave = wave >> 1, nwave = wave & 1;
  int l31 = lane & 31, khalf = lane >> 5;

  f32x16 acc[2][4];
#pragma unroll
  for (int s = 0; s < 2; ++s)
#pragma unroll
    for (int nt = 0; nt < 4; ++nt)
#pragma unroll
      for (int r = 0; r < 16; ++r) acc[s][nt][r] = 0.f;

  const char* aG[3];
  int aL[3];
#pragma unroll
  for (int i = 0; i < 3; ++i) {
    int px = (wave * 3 + i) * 16 + (lane >> 2);
    int s = lane & 3;
    int pxc = min(px, 179);
    int hy = pxc / 18, hx = pxc - hy * 18;
    int y = min(max(y0 - 1 + hy, 0), 255);
    int x = min(max(x0 - 1 + hx, 0), 255);
    int q = s ^ ((pxc >> 1) & 3);
    aG[i] = (const char*)actin +
            (((size_t)(b * 65536 + y * 256 + x)) * CI + q * 8) * 2;
    aL[i] = (wave * 3 + i) * 1024;
  }
  const char* bG = wr + wave * 4096 + lane * 16;
  int bL = wave * 4096;

#pragma unroll
  for (int i = 0; i < 3; ++i) dma16(aG[i], &As[0][aL[i]]);
#pragma unroll
  for (int i = 0; i < 4; ++i) dma16(bG + i * 1024, &Bs[0][bL + i * 1024]);
  __syncthreads();

  for (int cc = 0; cc < NC; ++cc) {
#pragma unroll
    for (int t = 0; t < 9; ++t) {
      int j = cc * 9 + t;
      if (j + 1 < NT) {
        const char* bsrc = bG + (size_t)(j + 1) * 16384;
        char* bdst = &Bs[(j + 1) & 1][bL];
#pragma unroll
        for (int i = 0; i < 4; ++i) dma16(bsrc + i * 1024, bdst + i * 1024);
        if (t == 8) {
#pragma unroll
          for (int i = 0; i < 3; ++i)
            dma16(aG[i] + (cc + 1) * 64, &As[(cc + 1) & 1][aL[i]]);
        }
      }
      int dy = t / 3, dx = t - dy * 3;
      const char* Ab = As[cc & 1];
      const char* Bb = Bs[j & 1];
      half8 af[2][2], bf[2][4];
#pragma unroll
      for (int s = 0; s < 2; ++s) {
        int px = (mwave * 4 + s * 2 + (l31 >> 4) + dy) * 18 + (l31 & 15) + dx;
        int sw = ((px >> 1) & 3) << 4;
#pragma unroll
        for (int ks = 0; ks < 2; ++ks) {
          int q = (ks * 2 + khalf) << 4;
          af[ks][s] = *(const half8*)(Ab + px * 64 + (q ^ sw));
        }
      }
#pragma unroll
      for (int nt = 0; nt < 4; ++nt) {
        int n = nwave * 128 + nt * 32 + l31;
        int sw = ((n >> 1) & 3) << 4;
#pragma unroll
        for (int ks = 0; ks < 2; ++ks) {
          int q = (ks * 2 + khalf) << 4;
          bf[ks][nt] = *(const half8*)(Bb + n * 64 + (q ^ sw));
        }
      }
#pragma unroll
      for (int ks = 0; ks < 2; ++ks)
#pragma unroll
        for (int s = 0; s < 2; ++s)
#pragma unroll
          for (int nt = 0; nt < 4; ++nt)
            acc[s][nt] = __builtin_amdgcn_mfma_f32_32x32x16_f16(
                af[ks][s], bf[ks][nt], acc[s][nt], 0, 0, 0);
      __syncthreads();
    }
  }

  // epilogue: bias + relu, store fp16
  // C/D: col = lane&31, row = (r&3) + 8*(r>>2) + 4*(lane>>5)
#pragma unroll
  for (int s = 0; s < 2; ++s)
#pragma unroll
    for (int nt = 0; nt < 4; ++nt) {
      int n = nwave * 128 + nt * 32 + l31;
      float bn = bias[n];
#pragma unroll
      for (int r = 0; r < 16; ++r) {
        int mrow = (r & 3) + 8 * (r >> 2) + 4 * khalf;
        int y = y0 + mwave * 4 + s * 2 + (mrow >> 4);
        int x = x0 + (mrow & 15);
        float v = fmaxf(acc[s][nt][r] + bn, 0.f);
        actout[(((size_t)(b * 65536 + y * 256 + x)) << 8) + n] = (_Float16)v;
      }
    }
}

// ---------------------------------------------------------------------------
// Head (one batch): logit_k(px) = wmu2_k . act2[px] + lgb[k]; softmax over
// 16; dot with label. One pixel per thread, all fp32 VALU. wmu2/lgb/label
// reads are wave-uniform -> scalar loads; no LDS, no spill (r3-proven).
// ---------------------------------------------------------------------------
__global__ __launch_bounds__(256) void k_head(
    const _Float16* __restrict__ act2, const float* __restrict__ wmu2,
    const float* __restrict__ lgb, const float* __restrict__ label,
    float* __restrict__ out) {
  int px = blockIdx.x * 256 + threadIdx.x;
  const half8* ap = (const half8*)(act2 + ((size_t)px << 8));
  float cr[16];
#pragma unroll
  for (int k = 0; k < 16; ++k) cr[k] = lgb[k];
#pragma unroll 2
  for (int cc = 0; cc < 32; ++cc) {
    half8 h = ap[cc];
    float a0 = (float)h[0], a1 = (float)h[1], a2 = (float)h[2],
          a3 = (float)h[3], a4 = (float)h[4], a5 = (float)h[5],
          a6 = (float)h[6], a7 = (float)h[7];
#pragma unroll
    for (int k = 0; k < 16; ++k) {
      const float* w = wmu2 + (k << 8) + (cc << 3);
      float c0 = cr[k];
      c0 = fmaf(a0, w[0], c0);
      c0 = fmaf(a1, w[1], c0);
      c0 = fmaf(a2, w[2], c0);
      c0 = fmaf(a3, w[3], c0);
      c0 = fmaf(a4, w[4], c0);
      c0 = fmaf(a5, w[5], c0);
      c0 = fmaf(a6, w[6], c0);
      c0 = fmaf(a7, w[7], c0);
      cr[k] = c0;
    }
  }
  float mx = cr[0];
#pragma unroll
  for (int k = 1; k < 16; ++k) mx = fmaxf(mx, cr[k]);
  float num = 0.f, den = 0.f;
#pragma unroll
  for (int k = 0; k < 16; ++k) {
    float e = __expf(cr[k] - mx);
    num = fmaf(e, label[k], num);
    den += e;
  }
  out[px] = num / den;
}

// ---------------------------------------------------------------------------
extern "C" void kernel_launch(void* const* d_in, const int* in_sizes, int n_in,
                              void* d_out, int out_size, void* d_ws, size_t ws_size,
                              hipStream_t stream) {
  const float* x  = (const float*)d_in[0];
  const float* w1 = (const float*)d_in[1];
  const float* b1 = (const float*)d_in[2];
  const float* w2 = (const float*)d_in[3];
  const float* b2 = (const float*)d_in[4];
  const float* w3 = (const float*)d_in[5];
  const float* b3 = (const float*)d_in[6];
  const float* mu = (const float*)d_in[7];
  const float* label = (const float*)d_in[8];
  float* out = (float*)d_out;

  char* ws = (char*)d_ws;
  _Float16* w1r  = (_Float16*)(ws + OFF_W1R);
  _Float16* w2r  = (_Float16*)(ws + OFF_W2R);
  float*    wmu2 = (float*)   (ws + OFF_WMU);
  float*    lgb  = (float*)   (ws + OFF_LGB);
  _Float16* act0 = (_Float16*)(ws + OFF_ACT0);   // [4][HW][64], 32 MB
  _Float16* act1 = (_Float16*)(ws + OFF_ACT1);   // [4][HW][256], 128 MB
  _Float16* act2 = (_Float16*)(ws + OFF_ACT0);   // [HW][256], aliases dead act0

  k_prep<<<2896, 256, 0, stream>>>(w1, w2, w3, b3, mu, w1r, w2r, wmu2, lgb);
  k_t0<<<4096, 256, 0, stream>>>(x, act0);
  // conv1 all batches in one dispatch (act0 fully consumed here)
  k_conv<64><<<2048, 256, 0, stream>>>(act0, (const char*)w1r, b1, act1);
  // per-batch conv2 (into act0's space) + head
  for (int b = 0; b < BB; ++b) {
    k_conv<256><<<512, 256, 0, stream>>>(act1 + (size_t)b * 65536 * 256,
                                         (const char*)w2r, b2, act2);
    k_head<<<256, 256, 0, stream>>>(act2, wmu2, lgb, label,
                                    out + (size_t)b * 65536);
  }
}

// Round 10
// 620.229 us; speedup vs baseline: 1.4941x; 1.2487x over previous
//
#include <hip/hip_runtime.h>

// Problem constants
#define BB   4
#define CIN  64
#define HH   256
#define WW   256
#define QQ   256
#define KK   16

typedef _Float16 half8 __attribute__((ext_vector_type(8)));
typedef float   f32x16 __attribute__((ext_vector_type(16)));
typedef unsigned int u32;

// ---- workspace layout (bytes); r8 proved ws_size >= 169378048 ----
// act0: fp16 [4][HW][64] = 32 MB (t0 out; dead after conv1 -> act2 of b=0)
// act1: fp16 [4][HW][256] = 128 MB; act1[b] dead after conv2(b) -> act2 of b+1
// wmu2 partials (128x256 fp32 = 131 KB) live at OFF_ACT1 until conv1 runs.
#define OFF_W1R   0ull
#define OFF_W2R   294912ull
#define OFF_WMU   1474560ull
#define OFF_LGB   1490944ull
#define OFF_ACT0  1605888ull
#define OFF_ACT1  35160320ull
// end of act1 = 169378048 = guaranteed ws floor

__device__ __forceinline__ void dma16(const void* g, void* l) {
  __builtin_amdgcn_global_load_lds(
      (const __attribute__((address_space(1))) u32*)g,
      (__attribute__((address_space(3))) u32*)l, 16, 0, 0);
}

// ---------------------------------------------------------------------------
// Prep. Blocks 0..575: w1r; 576..2879: w2r; 2880..3007: wmu2 partials
// (k=j>>3, o-chunk=j&7, coalesced w3 reads); 3008..3023: lgb.
// Weight image block (cc,tt)=16KB: 256 rows x 32ch; 16B-quarter q of row n
// stored at slot q^((n>>1)&3) (bank-group-uniform b128 reads).
// ---------------------------------------------------------------------------
__global__ __launch_bounds__(256) void k_prep(
    const float* __restrict__ w1, const float* __restrict__ w2,
    const float* __restrict__ w3, const float* __restrict__ b3,
    const float* __restrict__ mu,
    _Float16* __restrict__ w1r, _Float16* __restrict__ w2r,
    float* __restrict__ wpart, float* __restrict__ lgb) {
  int bid = blockIdx.x, tid = threadIdx.x;
  if (bid < 576) {                          // w1r (CI=64)
    int idx = bid * 256 + tid;
    int blk = idx >> 13;
    int cc = blk / 9, tt = blk - cc * 9;
    int rem = idx & 8191;
    int n = rem >> 5, r = rem & 31;
    int q = (r >> 3) ^ ((n >> 1) & 3), e = r & 7;
    int c = cc * 32 + q * 8 + e;
    w1r[idx] = (_Float16)w1[(n * 64 + c) * 9 + tt];
  } else if (bid < 2880) {                  // w2r (CI=256)
    int d = (bid - 576) * 256 + tid;
    int blk = d >> 13;
    int cc = blk / 9, tt = blk - cc * 9;
    int rem = d & 8191;
    int n = rem >> 5, r = rem & 31;
    int q = (r >> 3) ^ ((n >> 1) & 3), e = r & 7;
    int c = cc * 32 + q * 8 + e;
    w2r[d] = (_Float16)w2[(n * 256 + c) * 9 + tt];
  } else if (bid < 3008) {                  // wmu2 partials
    int j = bid - 2880;
    int k = j >> 3, o0 = (j & 7) << 5;
    float s = 0.f;
#pragma unroll 4
    for (int oi = 0; oi < 32; ++oi) {
      int o = o0 + oi;
      s = fmaf(mu[k * 256 + o], w3[o * 256 + tid], s);
    }
    wpart[j * 256 + tid] = s;
  } else {                                  // lgb, one block per k
    int k = bid - 3008;
    float m = mu[k * 256 + tid];
    __shared__ float red[256];
    red[tid] = m * (2.f * b3[tid] - m);
    __syncthreads();
    for (int st = 128; st > 0; st >>= 1) {
      if (tid < st) red[tid] += red[tid + st];
      __syncthreads();
    }
    if (tid == 0) lgb[k] = red[0];
  }
}

// Reduce wmu2 partials: wmu2[k][c] = 2 * sum_p wpart[k*8+p][c]. 16 blocks.
__global__ __launch_bounds__(256) void k_prep2(
    const float* __restrict__ wpart, float* __restrict__ wmu2) {
  int k = blockIdx.x, tid = threadIdx.x;
  float s = 0.f;
#pragma unroll
  for (int p = 0; p < 8; ++p) s += wpart[(k * 8 + p) * 256 + tid];
  wmu2[k * 256 + tid] = 2.f * s;
}

// ---------------------------------------------------------------------------
// T0: x NCHW fp32 -> act0 [b][HW][64] fp16, all 4 batches. grid 4096.
// ---------------------------------------------------------------------------
__global__ __launch_bounds__(256) void k_t0(const float* __restrict__ x,
                                            _Float16* __restrict__ act0) {
  __shared__ float tile[64][65];
  int blk = blockIdx.x;
  int b = blk >> 10;
  int p0 = (blk & 1023) << 6;
  int t = threadIdx.x;
  {
    int p = t & 63, c0 = t >> 6;
    const float* xb = x + (size_t)b * (CIN * 65536) + p0 + p;
#pragma unroll
    for (int i = 0; i < 16; ++i) {
      int c = c0 + (i << 2);
      tile[c][p] = xb[(size_t)c * 65536];
    }
  }
  __syncthreads();
  {
    // 512 (px, c-octet) units; thread t covers units t and t+256.
    _Float16* o = act0 + (size_t)(b * 65536 + p0) * CIN;
#pragma unroll
    for (int uu = 0; uu < 2; ++uu) {
      int u = t + (uu << 8);
      int px = u & 63, oct = u >> 6;
      half8 h;
#pragma unroll
      for (int i = 0; i < 8; ++i) h[i] = (_Float16)tile[oct * 8 + i][px];
      *(half8*)(o + px * CIN + oct * 8) = h;
    }
  }
}

// ---------------------------------------------------------------------------
// Conv 3x3 (replicate pad) + bias + ReLU, 32x32x16 fp16 MFMA, DMA staging,
// XOR-swizzled LDS (slot = q ^ ((row>>1)&3)). Block: 128 px x 256 ch.
// grid 512*NB; b = blockIdx>>9 (pass batch-sliced pointers for per-batch).
// ---------------------------------------------------------------------------
template <int CI>
__global__ __launch_bounds__(256, 2) void k_conv(
    const _Float16* __restrict__ actin, const char* __restrict__ wr,
    const float* __restrict__ bias, _Float16* __restrict__ actout) {
  constexpr int NC = CI / 32;
  constexpr int NT = 9 * NC;
  __shared__ __align__(16) char As[2][12288];
  __shared__ __align__(16) char Bs[2][16384];

  int tid = threadIdx.x;
  int b = blockIdx.x >> 9;
  int tile = blockIdx.x & 511;
  int txi = tile & 15, tyi = tile >> 4;
  int x0 = txi << 4, y0 = tyi << 3;
  int lane = tid & 63, wave = tid >> 6;
  int mwave = wave >> 1, nwave = wave & 1;
  int l31 = lane & 31, khalf = lane >> 5;

  f32x16 acc[2][4];
#pragma unroll
  for (int s = 0; s < 2; ++s)
#pragma unroll
    for (int nt = 0; nt < 4; ++nt)
#pragma unroll
      for (int r = 0; r < 16; ++r) acc[s][nt][r] = 0.f;

  const char* aG[3];
  int aL[3];
#pragma unroll
  for (int i = 0; i < 3; ++i) {
    int px = (wave * 3 + i) * 16 + (lane >> 2);
    int s = lane & 3;
    int pxc = min(px, 179);
    int hy = pxc / 18, hx = pxc - hy * 18;
    int y = min(max(y0 - 1 + hy, 0), 255);
    int x = min(max(x0 - 1 + hx, 0), 255);
    int q = s ^ ((pxc >> 1) & 3);
    aG[i] = (const char*)actin +
            (((size_t)(b * 65536 + y * 256 + x)) * CI + q * 8) * 2;
    aL[i] = (wave * 3 + i) * 1024;
  }
  const char* bG = wr + wave * 4096 + lane * 16;
  int bL = wave * 4096;

#pragma unroll
  for (int i = 0; i < 3; ++i) dma16(aG[i], &As[0][aL[i]]);
#pragma unroll
  for (int i = 0; i < 4; ++i) dma16(bG + i * 1024, &Bs[0][bL + i * 1024]);
  __syncthreads();

  for (int cc = 0; cc < NC; ++cc) {
#pragma unroll
    for (int t = 0; t < 9; ++t) {
      int j = cc * 9 + t;
      if (j + 1 < NT) {
        const char* bsrc = bG + (size_t)(j + 1) * 16384;
        char* bdst = &Bs[(j + 1) & 1][bL];
#pragma unroll
        for (int i = 0; i < 4; ++i) dma16(bsrc + i * 1024, bdst + i * 1024);
        if (t == 8) {
#pragma unroll
          for (int i = 0; i < 3; ++i)
            dma16(aG[i] + (cc + 1) * 64, &As[(cc + 1) & 1][aL[i]]);
        }
      }
      int dy = t / 3, dx = t - dy * 3;
      const char* Ab = As[cc & 1];
      const char* Bb = Bs[j & 1];
      half8 af[2][2], bf[2][4];
#pragma unroll
      for (int s = 0; s < 2; ++s) {
        int px = (mwave * 4 + s * 2 + (l31 >> 4) + dy) * 18 + (l31 & 15) + dx;
        int sw = ((px >> 1) & 3) << 4;
#pragma unroll
        for (int ks = 0; ks < 2; ++ks) {
          int q = (ks * 2 + khalf) << 4;
          af[ks][s] = *(const half8*)(Ab + px * 64 + (q ^ sw));
        }
      }
#pragma unroll
      for (int nt = 0; nt < 4; ++nt) {
        int n = nwave * 128 + nt * 32 + l31;
        int sw = ((n >> 1) & 3) << 4;
#pragma unroll
        for (int ks = 0; ks < 2; ++ks) {
          int q = (ks * 2 + khalf) << 4;
          bf[ks][nt] = *(const half8*)(Bb + n * 64 + (q ^ sw));
        }
      }
#pragma unroll
      for (int ks = 0; ks < 2; ++ks)
#pragma unroll
        for (int s = 0; s < 2; ++s)
#pragma unroll
          for (int nt = 0; nt < 4; ++nt)
            acc[s][nt] = __builtin_amdgcn_mfma_f32_32x32x16_f16(
                af[ks][s], bf[ks][nt], acc[s][nt], 0, 0, 0);
      __syncthreads();
    }
  }

  // epilogue: bias + relu, store fp16
  // C/D: col = lane&31, row = (r&3) + 8*(r>>2) + 4*(lane>>5)
#pragma unroll
  for (int s = 0; s < 2; ++s)
#pragma unroll
    for (int nt = 0; nt < 4; ++nt) {
      int n = nwave * 128 + nt * 32 + l31;
      float bn = bias[n];
#pragma unroll
      for (int r = 0; r < 16; ++r) {
        int mrow = (r & 3) + 8 * (r >> 2) + 4 * khalf;
        int y = y0 + mwave * 4 + s * 2 + (mrow >> 4);
        int x = x0 + (mrow & 15);
        float v = fmaxf(acc[s][nt][r] + bn, 0.f);
        actout[(((size_t)(b * 65536 + y * 256 + x)) << 8) + n] = (_Float16)v;
      }
    }
}

// ---------------------------------------------------------------------------
// Head, all 4 batches in one dispatch (act2 of each batch lives in a
// different dead region; pointers passed individually). One px per thread,
// all fp32 VALU; wmu2/lgb/label wave-uniform -> scalar loads. grid 1024.
// ---------------------------------------------------------------------------
__global__ __launch_bounds__(256) void k_head(
    const _Float16* __restrict__ a2_0, const _Float16* __restrict__ a2_1,
    const _Float16* __restrict__ a2_2, const _Float16* __restrict__ a2_3,
    const float* __restrict__ wmu2, const float* __restrict__ lgb,
    const float* __restrict__ label, float* __restrict__ out) {
  int b = blockIdx.x >> 8;
  int px = (blockIdx.x & 255) * 256 + threadIdx.x;
  const _Float16* base = (b == 0) ? a2_0 : (b == 1) ? a2_1
                       : (b == 2) ? a2_2 : a2_3;
  const half8* ap = (const half8*)(base + ((size_t)px << 8));
  float cr[16];
#pragma unroll
  for (int k = 0; k < 16; ++k) cr[k] = lgb[k];
#pragma unroll 2
  for (int cc = 0; cc < 32; ++cc) {
    half8 h = ap[cc];
    float a0 = (float)h[0], a1 = (float)h[1], a2 = (float)h[2],
          a3 = (float)h[3], a4 = (float)h[4], a5 = (float)h[5],
          a6 = (float)h[6], a7 = (float)h[7];
#pragma unroll
    for (int k = 0; k < 16; ++k) {
      const float* w = wmu2 + (k << 8) + (cc << 3);
      float c0 = cr[k];
      c0 = fmaf(a0, w[0], c0);
      c0 = fmaf(a1, w[1], c0);
      c0 = fmaf(a2, w[2], c0);
      c0 = fmaf(a3, w[3], c0);
      c0 = fmaf(a4, w[4], c0);
      c0 = fmaf(a5, w[5], c0);
      c0 = fmaf(a6, w[6], c0);
      c0 = fmaf(a7, w[7], c0);
      cr[k] = c0;
    }
  }
  float mx = cr[0];
#pragma unroll
  for (int k = 1; k < 16; ++k) mx = fmaxf(mx, cr[k]);
  float num = 0.f, den = 0.f;
#pragma unroll
  for (int k = 0; k < 16; ++k) {
    float e = __expf(cr[k] - mx);
    num = fmaf(e, label[k], num);
    den += e;
  }
  out[(size_t)b * 65536 + px] = num / den;
}

// ---------------------------------------------------------------------------
extern "C" void kernel_launch(void* const* d_in, const int* in_sizes, int n_in,
                              void* d_out, int out_size, void* d_ws, size_t ws_size,
                              hipStream_t stream) {
  const float* x  = (const float*)d_in[0];
  const float* w1 = (const float*)d_in[1];
  const float* b1 = (const float*)d_in[2];
  const float* w2 = (const float*)d_in[3];
  const float* b2 = (const float*)d_in[4];
  const float* w3 = (const float*)d_in[5];
  const float* b3 = (const float*)d_in[6];
  const float* mu = (const float*)d_in[7];
  const float* label = (const float*)d_in[8];
  float* out = (float*)d_out;

  char* ws = (char*)d_ws;
  _Float16* w1r  = (_Float16*)(ws + OFF_W1R);
  _Float16* w2r  = (_Float16*)(ws + OFF_W2R);
  float*    wmu2 = (float*)   (ws + OFF_WMU);
  float*    lgb  = (float*)   (ws + OFF_LGB);
  _Float16* act0 = (_Float16*)(ws + OFF_ACT0);   // [4][HW][64], 32 MB
  _Float16* act1 = (_Float16*)(ws + OFF_ACT1);   // [4][HW][256], 128 MB
  float*    wpart = (float*)  (ws + OFF_ACT1);   // 131 KB, dead before conv1

  // act2(b) destinations: all in regions dead at time of write
  _Float16* a2d[4] = {
    (_Float16*)(ws + OFF_ACT0),                          // b=0: act0 (dead)
    act1 + 0 * (size_t)65536 * 256,                      // b=1: act1[0] (dead)
    act1 + 1 * (size_t)65536 * 256,                      // b=2: act1[1] (dead)
    act1 + 2 * (size_t)65536 * 256                       // b=3: act1[2] (dead)
  };

  k_prep<<<3024, 256, 0, stream>>>(w1, w2, w3, b3, mu, w1r, w2r, wpart, lgb);
  k_prep2<<<16, 256, 0, stream>>>(wpart, wmu2);
  k_t0<<<4096, 256, 0, stream>>>(x, act0);
  k_conv<64><<<2048, 256, 0, stream>>>(act0, (const char*)w1r, b1, act1);
  for (int b = 0; b < BB; ++b)
    k_conv<256><<<512, 256, 0, stream>>>(act1 + (size_t)b * 65536 * 256,
                                         (const char*)w2r, b2, a2d[b]);
  k_head<<<1024, 256, 0, stream>>>(a2d[0], a2d[1], a2d[2], a2d[3],
                                   wmu2, lgb, label, out);
}

// Round 11
// 587.998 us; speedup vs baseline: 1.5760x; 1.0548x over previous
//
#include <hip/hip_runtime.h>

// Problem constants
#define BB   4
#define CIN  64
#define HH   256
#define WW   256
#define QQ   256
#define KK   16

typedef _Float16 half8 __attribute__((ext_vector_type(8)));
typedef float   f32x16 __attribute__((ext_vector_type(16)));
typedef unsigned int u32;

// ---- workspace layout (bytes); r8 proved ws_size >= 169378048 ----
// act0: fp16 [4][HW][64] = 32 MB (t0 out; dead after conv1 -> act2 of b=0)
// act1: fp16 [4][HW][256] = 128 MB; act1[b] dead after conv2(b) -> act2 of b+1
// wmu2 partials (128x256 fp32 = 131 KB) live at OFF_ACT1 until conv1 runs.
#define OFF_W1R   0ull
#define OFF_W2R   294912ull
#define OFF_WMU   1474560ull
#define OFF_LGB   1490944ull
#define OFF_ACT0  1605888ull
#define OFF_ACT1  35160320ull
// end of act1 = 169378048 = guaranteed ws floor

__device__ __forceinline__ void dma16(const void* g, void* l) {
  __builtin_amdgcn_global_load_lds(
      (const __attribute__((address_space(1))) u32*)g,
      (__attribute__((address_space(3))) u32*)l, 16, 0, 0);
}

// ---------------------------------------------------------------------------
// Prep. Blocks 0..575: w1r; 576..2879: w2r; 2880..3007: wmu2 partials
// (k=j>>3, o-chunk=j&7, coalesced w3 reads); 3008..3023: lgb.
// Weight image block (cc,tt)=16KB: 256 rows x 32ch; 16B-quarter q of row n
// stored at slot q^((n>>1)&3) (bank-group-uniform b128 reads).
// ---------------------------------------------------------------------------
__global__ __launch_bounds__(256) void k_prep(
    const float* __restrict__ w1, const float* __restrict__ w2,
    const float* __restrict__ w3, const float* __restrict__ b3,
    const float* __restrict__ mu,
    _Float16* __restrict__ w1r, _Float16* __restrict__ w2r,
    float* __restrict__ wpart, float* __restrict__ lgb) {
  int bid = blockIdx.x, tid = threadIdx.x;
  if (bid < 576) {                          // w1r (CI=64)
    int idx = bid * 256 + tid;
    int blk = idx >> 13;
    int cc = blk / 9, tt = blk - cc * 9;
    int rem = idx & 8191;
    int n = rem >> 5, r = rem & 31;
    int q = (r >> 3) ^ ((n >> 1) & 3), e = r & 7;
    int c = cc * 32 + q * 8 + e;
    w1r[idx] = (_Float16)w1[(n * 64 + c) * 9 + tt];
  } else if (bid < 2880) {                  // w2r (CI=256)
    int d = (bid - 576) * 256 + tid;
    int blk = d >> 13;
    int cc = blk / 9, tt = blk - cc * 9;
    int rem = d & 8191;
    int n = rem >> 5, r = rem & 31;
    int q = (r >> 3) ^ ((n >> 1) & 3), e = r & 7;
    int c = cc * 32 + q * 8 + e;
    w2r[d] = (_Float16)w2[(n * 256 + c) * 9 + tt];
  } else if (bid < 3008) {                  // wmu2 partials
    int j = bid - 2880;
    int k = j >> 3, o0 = (j & 7) << 5;
    float s = 0.f;
#pragma unroll 4
    for (int oi = 0; oi < 32; ++oi) {
      int o = o0 + oi;
      s = fmaf(mu[k * 256 + o], w3[o * 256 + tid], s);
    }
    wpart[j * 256 + tid] = s;
  } else {                                  // lgb, one block per k
    int k = bid - 3008;
    float m = mu[k * 256 + tid];
    __shared__ float red[256];
    red[tid] = m * (2.f * b3[tid] - m);
    __syncthreads();
    for (int st = 128; st > 0; st >>= 1) {
      if (tid < st) red[tid] += red[tid + st];
      __syncthreads();
    }
    if (tid == 0) lgb[k] = red[0];
  }
}

// Reduce wmu2 partials: wmu2[k][c] = 2 * sum_p wpart[k*8+p][c]. 16 blocks.
__global__ __launch_bounds__(256) void k_prep2(
    const float* __restrict__ wpart, float* __restrict__ wmu2) {
  int k = blockIdx.x, tid = threadIdx.x;
  float s = 0.f;
#pragma unroll
  for (int p = 0; p < 8; ++p) s += wpart[(k * 8 + p) * 256 + tid];
  wmu2[k * 256 + tid] = 2.f * s;
}

// ---------------------------------------------------------------------------
// T0: x NCHW fp32 -> act0 [b][HW][64] fp16, all 4 batches. grid 4096.
// ---------------------------------------------------------------------------
__global__ __launch_bounds__(256) void k_t0(const float* __restrict__ x,
                                            _Float16* __restrict__ act0) {
  __shared__ float tile[64][65];
  int blk = blockIdx.x;
  int b = blk >> 10;
  int p0 = (blk & 1023) << 6;
  int t = threadIdx.x;
  {
    int p = t & 63, c0 = t >> 6;
    const float* xb = x + (size_t)b * (CIN * 65536) + p0 + p;
#pragma unroll
    for (int i = 0; i < 16; ++i) {
      int c = c0 + (i << 2);
      tile[c][p] = xb[(size_t)c * 65536];
    }
  }
  __syncthreads();
  {
    // 512 (px, c-octet) units; thread t covers units t and t+256.
    _Float16* o = act0 + (size_t)(b * 65536 + p0) * CIN;
#pragma unroll
    for (int uu = 0; uu < 2; ++uu) {
      int u = t + (uu << 8);
      int px = u & 63, oct = u >> 6;
      half8 h;
#pragma unroll
      for (int i = 0; i < 8; ++i) h[i] = (_Float16)tile[oct * 8 + i][px];
      *(half8*)(o + px * CIN + oct * 8) = h;
    }
  }
}

// ---------------------------------------------------------------------------
// Conv 3x3 (replicate pad) + bias + ReLU, 32x32x16 fp16 MFMA, DMA staging,
// XOR-swizzled LDS (slot = q ^ ((row>>1)&3)). Block: 128 px x 256 ch.
// Epilogue: stage C-tile in LDS ([px][264] fp16) then fully-coalesced
// dwordx4 global stores (1 KB contiguous per wave-instr).
// grid 512*NB; b = blockIdx>>9.
// ---------------------------------------------------------------------------
template <int CI>
__global__ __launch_bounds__(256, 2) void k_conv(
    const _Float16* __restrict__ actin, const char* __restrict__ wr,
    const float* __restrict__ bias, _Float16* __restrict__ actout) {
  constexpr int NC = CI / 32;
  constexpr int NT = 9 * NC;
  __shared__ __align__(16) char smem[67584];   // As(24576)+Bs(32768) | Qs
  auto As = (char(*)[12288])smem;
  auto Bs = (char(*)[16384])(smem + 24576);
  _Float16* Qs = (_Float16*)smem;              // [128][264] fp16 (epilogue)

  int tid = threadIdx.x;
  int b = blockIdx.x >> 9;
  int tile = blockIdx.x & 511;
  int txi = tile & 15, tyi = tile >> 4;
  int x0 = txi << 4, y0 = tyi << 3;
  int lane = tid & 63, wave = tid >> 6;
  int mwave = wave >> 1, nwave = wave & 1;
  int l31 = lane & 31, khalf = lane >> 5;

  f32x16 acc[2][4];
#pragma unroll
  for (int s = 0; s < 2; ++s)
#pragma unroll
    for (int nt = 0; nt < 4; ++nt)
#pragma unroll
      for (int r = 0; r < 16; ++r) acc[s][nt][r] = 0.f;

  const char* aG[3];
  int aL[3];
#pragma unroll
  for (int i = 0; i < 3; ++i) {
    int px = (wave * 3 + i) * 16 + (lane >> 2);
    int s = lane & 3;
    int pxc = min(px, 179);
    int hy = pxc / 18, hx = pxc - hy * 18;
    int y = min(max(y0 - 1 + hy, 0), 255);
    int x = min(max(x0 - 1 + hx, 0), 255);
    int q = s ^ ((pxc >> 1) & 3);
    aG[i] = (const char*)actin +
            (((size_t)(b * 65536 + y * 256 + x)) * CI + q * 8) * 2;
    aL[i] = (wave * 3 + i) * 1024;
  }
  const char* bG = wr + wave * 4096 + lane * 16;
  int bL = wave * 4096;

#pragma unroll
  for (int i = 0; i < 3; ++i) dma16(aG[i], &As[0][aL[i]]);
#pragma unroll
  for (int i = 0; i < 4; ++i) dma16(bG + i * 1024, &Bs[0][bL + i * 1024]);
  __syncthreads();

  for (int cc = 0; cc < NC; ++cc) {
#pragma unroll
    for (int t = 0; t < 9; ++t) {
      int j = cc * 9 + t;
      if (j + 1 < NT) {
        const char* bsrc = bG + (size_t)(j + 1) * 16384;
        char* bdst = &Bs[(j + 1) & 1][bL];
#pragma unroll
        for (int i = 0; i < 4; ++i) dma16(bsrc + i * 1024, bdst + i * 1024);
        if (t == 8) {
#pragma unroll
          for (int i = 0; i < 3; ++i)
            dma16(aG[i] + (cc + 1) * 64, &As[(cc + 1) & 1][aL[i]]);
        }
      }
      int dy = t / 3, dx = t - dy * 3;
      const char* Ab = As[cc & 1];
      const char* Bb = Bs[j & 1];
      half8 af[2][2], bf[2][4];
#pragma unroll
      for (int s = 0; s < 2; ++s) {
        int px = (mwave * 4 + s * 2 + (l31 >> 4) + dy) * 18 + (l31 & 15) + dx;
        int sw = ((px >> 1) & 3) << 4;
#pragma unroll
        for (int ks = 0; ks < 2; ++ks) {
          int q = (ks * 2 + khalf) << 4;
          af[ks][s] = *(const half8*)(Ab + px * 64 + (q ^ sw));
        }
      }
#pragma unroll
      for (int nt = 0; nt < 4; ++nt) {
        int n = nwave * 128 + nt * 32 + l31;
        int sw = ((n >> 1) & 3) << 4;
#pragma unroll
        for (int ks = 0; ks < 2; ++ks) {
          int q = (ks * 2 + khalf) << 4;
          bf[ks][nt] = *(const half8*)(Bb + n * 64 + (q ^ sw));
        }
      }
#pragma unroll
      for (int ks = 0; ks < 2; ++ks)
#pragma unroll
        for (int s = 0; s < 2; ++s)
#pragma unroll
          for (int nt = 0; nt < 4; ++nt)
            acc[s][nt] = __builtin_amdgcn_mfma_f32_32x32x16_f16(
                af[ks][s], bf[ks][nt], acc[s][nt], 0, 0, 0);
      __syncthreads();   // drains DMA; after last tap As/Bs are dead
    }
  }

  // ---- epilogue: bias+relu, stage to LDS [px][264], coalesced stores ----
  // C/D: col = lane&31, row = (r&3) + 8*(r>>2) + 4*(lane>>5)
#pragma unroll
  for (int s = 0; s < 2; ++s)
#pragma unroll
    for (int nt = 0; nt < 4; ++nt) {
      int n = nwave * 128 + nt * 32 + l31;
      float bn = bias[n];
#pragma unroll
      for (int r = 0; r < 16; ++r) {
        int mrow = (r & 3) + 8 * (r >> 2) + 4 * khalf;
        int p = (mwave * 4 + s * 2 + (mrow >> 4)) * 16 + (mrow & 15);
        Qs[p * 264 + n] = (_Float16)fmaxf(acc[s][nt][r] + bn, 0.f);
      }
    }
  __syncthreads();
  {
    _Float16* gout = actout + (((size_t)(b * 65536 + y0 * 256 + x0)) << 8);
#pragma unroll
    for (int i = 0; i < 16; ++i) {
      int f = tid + (i << 8);
      int p = f >> 5, o = f & 31;
      half8 v = *(const half8*)&Qs[p * 264 + o * 8];
      *(half8*)(gout + (((p >> 4) * 256 + (p & 15)) << 8) + o * 8) = v;
    }
  }
}

// ---------------------------------------------------------------------------
// Head, all 4 batches in one dispatch. One px per thread, all fp32 VALU;
// wmu2/lgb/label wave-uniform -> scalar loads. grid 1024.
// ---------------------------------------------------------------------------
__global__ __launch_bounds__(256) void k_head(
    const _Float16* __restrict__ a2_0, const _Float16* __restrict__ a2_1,
    const _Float16* __restrict__ a2_2, const _Float16* __restrict__ a2_3,
    const float* __restrict__ wmu2, const float* __restrict__ lgb,
    const float* __restrict__ label, float* __restrict__ out) {
  int b = blockIdx.x >> 8;
  int px = (blockIdx.x & 255) * 256 + threadIdx.x;
  const _Float16* base = (b == 0) ? a2_0 : (b == 1) ? a2_1
                       : (b == 2) ? a2_2 : a2_3;
  const half8* ap = (const half8*)(base + ((size_t)px << 8));
  float cr[16];
#pragma unroll
  for (int k = 0; k < 16; ++k) cr[k] = lgb[k];
#pragma unroll 2
  for (int cc = 0; cc < 32; ++cc) {
    half8 h = ap[cc];
    float a0 = (float)h[0], a1 = (float)h[1], a2 = (float)h[2],
          a3 = (float)h[3], a4 = (float)h[4], a5 = (float)h[5],
          a6 = (float)h[6], a7 = (float)h[7];
#pragma unroll
    for (int k = 0; k < 16; ++k) {
      const float* w = wmu2 + (k << 8) + (cc << 3);
      float c0 = cr[k];
      c0 = fmaf(a0, w[0], c0);
      c0 = fmaf(a1, w[1], c0);
      c0 = fmaf(a2, w[2], c0);
      c0 = fmaf(a3, w[3], c0);
      c0 = fmaf(a4, w[4], c0);
      c0 = fmaf(a5, w[5], c0);
      c0 = fmaf(a6, w[6], c0);
      c0 = fmaf(a7, w[7], c0);
      cr[k] = c0;
    }
  }
  float mx = cr[0];
#pragma unroll
  for (int k = 1; k < 16; ++k) mx = fmaxf(mx, cr[k]);
  float num = 0.f, den = 0.f;
#pragma unroll
  for (int k = 0; k < 16; ++k) {
    float e = __expf(cr[k] - mx);
    num = fmaf(e, label[k], num);
    den += e;
  }
  out[(size_t)b * 65536 + px] = num / den;
}

// ---------------------------------------------------------------------------
extern "C" void kernel_launch(void* const* d_in, const int* in_sizes, int n_in,
                              void* d_out, int out_size, void* d_ws, size_t ws_size,
                              hipStream_t stream) {
  const float* x  = (const float*)d_in[0];
  const float* w1 = (const float*)d_in[1];
  const float* b1 = (const float*)d_in[2];
  const float* w2 = (const float*)d_in[3];
  const float* b2 = (const float*)d_in[4];
  const float* w3 = (const float*)d_in[5];
  const float* b3 = (const float*)d_in[6];
  const float* mu = (const float*)d_in[7];
  const float* label = (const float*)d_in[8];
  float* out = (float*)d_out;

  char* ws = (char*)d_ws;
  _Float16* w1r  = (_Float16*)(ws + OFF_W1R);
  _Float16* w2r  = (_Float16*)(ws + OFF_W2R);
  float*    wmu2 = (float*)   (ws + OFF_WMU);
  float*    lgb  = (float*)   (ws + OFF_LGB);
  _Float16* act0 = (_Float16*)(ws + OFF_ACT0);   // [4][HW][64], 32 MB
  _Float16* act1 = (_Float16*)(ws + OFF_ACT1);   // [4][HW][256], 128 MB
  float*    wpart = (float*)  (ws + OFF_ACT1);   // 131 KB, dead before conv1

  // act2(b) destinations: all in regions dead at time of write
  _Float16* a2d[4] = {
    (_Float16*)(ws + OFF_ACT0),                          // b=0: act0 (dead)
    act1 + 0 * (size_t)65536 * 256,                      // b=1: act1[0] (dead)
    act1 + 1 * (size_t)65536 * 256,                      // b=2: act1[1] (dead)
    act1 + 2 * (size_t)65536 * 256                       // b=3: act1[2] (dead)
  };

  k_prep<<<3024, 256, 0, stream>>>(w1, w2, w3, b3, mu, w1r, w2r, wpart, lgb);
  k_prep2<<<16, 256, 0, stream>>>(wpart, wmu2);
  k_t0<<<4096, 256, 0, stream>>>(x, act0);
  k_conv<64><<<2048, 256, 0, stream>>>(act0, (const char*)w1r, b1, act1);
  for (int b = 0; b < BB; ++b)
    k_conv<256><<<512, 256, 0, stream>>>(act1 + (size_t)b * 65536 * 256,
                                         (const char*)w2r, b2, a2d[b]);
  k_head<<<1024, 256, 0, stream>>>(a2d[0], a2d[1], a2d[2], a2d[3],
                                   wmu2, lgb, label, out);
}